// Round 17
// baseline (78.947 us; speedup 1.0000x reference)
//
#include <hip/hip_runtime.h>
#include <math.h>

#define HH 32
#define WW 32
#define CIN 64
#define NO 64
#define NCK 576                 // CIN*9
#define X_ELEMS 262144
#define WSTRIDE 65              // LDS W row stride (65: conflict-free scatter + 2-way read alias)

__device__ __forceinline__ float fexp2(float x) {
#if __has_builtin(__builtin_amdgcn_exp2f)
    return __builtin_amdgcn_exp2f(x);
#else
    return exp2f(x);
#endif
}
__device__ __forceinline__ float flog2(float x) {
#if __has_builtin(__builtin_amdgcn_logf)
    return __builtin_amdgcn_logf(x);
#else
    return log2f(x);
#endif
}

// Single dispatch. Block = 1024 thr = 16 waves = 16 whole pixels; grid = 256
// = exactly 1 block/CU. Each block:
//  (1) stages W[ck][o] = -SZ*theta[o][ck] into LDS (149.8 KB, stride-65);
//  (2) computes tau[ck] = -max_o W - 8 from LDS;
//  (3) per wave (lane = o, pixel = blockIdx*16 + wave): 10 up-front x-gathers,
//      10 ballots (7ch x 9taps each), then ctz-quad evaluation with W from
//      LDS (no global latency, no worklist, no c-half combine).
__global__ __launch_bounds__(1024) void ekv_kernel(
        const float* __restrict__ x, const float* __restrict__ theta,
        float* __restrict__ out) {
    constexpr float SZ = 19.235933878519512f;    // log2(e)/0.075
    constexpr float C2 = 1.2726342e-3f;          // 2^(-D2), D2 = 0.5/(0.075*ln2)
    constexpr float OS = 0.020018875579925058f;  // ln2^2 * 2e-6 * 500000/24

    __shared__ float Wl[NCK * WSTRIDE];          // 149.76 KB
    __shared__ float taul[NCK + 64];             // 2.5 KB (pad: never active)

    const int t = threadIdx.x;

    // ---- stage W (coalesced theta reads; LDS scatter stride-65 = conflict-free) ----
#pragma unroll
    for (int j = 0; j < 36; ++j) {               // 36864 / 1024
        int i  = t + 1024 * j;                   // i = o*576 + ck (theta flat)
        int o  = i / NCK;
        int ck = i - NCK * o;
        Wl[ck * WSTRIDE + o] = -SZ * theta[i];
    }
    __syncthreads();

    // ---- tau[ck] = SZ*min_o theta - 8 = -max_o W - 8 ----
    if (t < NCK) {
        float mx = -1e30f;
        for (int o = 0; o < 64; ++o) mx = fmaxf(mx, Wl[t * WSTRIDE + o]);
        taul[t] = -mx - 8.0f;                    // active iff z >= -8
    } else if (t < NCK + 64) {
        taul[t] = 1e30f;                         // pad
    }
    __syncthreads();

    const int lane = t & 63;
    const int wv   = __builtin_amdgcn_readfirstlane(t >> 6);  // 0..15
    const int pix  = (int)blockIdx.x * 16 + wv;
    const int n  = pix >> 10;
    const int ho = (pix >> 5) & 31;
    const int wo = pix & 31;

    // lane l -> (c_off = l/9, tap k = l%9); lane 63 decode-clamped + masked
    int l = lane;
    int c_off = l / 9; if (c_off > 6) c_off = 6;
    int k = l - 9 * c_off; if (k > 8) k = 8;
    int di = k / 3, dj = k - 3 * (k / 3);
    int h = ho + di - 1, w_ = wo + dj - 1;
    bool sval = (h >= 0) && (h < HH) && (w_ >= 0) && (w_ < WW);
    int hc = min(max(h, 0), HH - 1), wc = min(max(w_, 0), WW - 1);
    // pad taps: xs = 0 == exact x=0 contribution if ever active; else skipped
    float msc = ((l < 63) && sval) ? SZ : 0.0f;

    const int g0 = n * (CIN * HH * WW) + c_off * 1024 + hc * WW + wc;

    // all 10 x-gathers issued up-front (independent; one vmcnt ladder)
    float xv[10];
#pragma unroll
    for (int i = 0; i < 10; ++i) {
        int g = g0 + i * 7 * 1024;
        xv[i] = x[min(g, X_ELEMS - 1)];          // OOB lanes masked by cc test
    }

    // 10 ballots: chunk i covers channels 7i .. 7i+cc-1 (cc = min(64-7i, 7))
    float xsv[10];
    unsigned long long act[10];
#pragma unroll
    for (int i = 0; i < 10; ++i) {
        const int cb = i * 7;
        const int cc = (64 - cb) < 7 ? (64 - cb) : 7;
        float xs = xv[i] * msc;                  // SZ*x (pad lanes: 0)
        float tv = taul[cb * 9 + l];             // l=63 -> <=630, in-bounds
        xsv[i] = xs;
        bool a = (xs >= tv) && (l < cc * 9);
        act[i] = __ballot(a);
    }

    float accF = 0.f, accR = 0.f;

#define EKV_BODY(II, WV, EN)                                               \
    {                                                                      \
        int xb = __builtin_amdgcn_readlane(                                \
                     __builtin_bit_cast(int, xs), (II));                   \
        float sx = __builtin_bit_cast(float, xb);                          \
        float z  = (EN) ? (WV) + sx : -200.0f;   /* SZ*(x - theta) */      \
        float e  = fexp2(z);                                               \
        float f  = flog2(1.0f + e);                                        \
        float rr = flog2(fmaf(C2, e, 1.0f));                               \
        accF = fmaf(f, f, accF);                                           \
        accR = fmaf(rr, rr, accR);                                         \
    }

#pragma unroll 1
    for (int i = 0; i < 10; ++i) {
        unsigned long long m = act[i];
        const int cb9 = i * 63;                  // ck = cb9 + il (il = lane idx)
        const float xs = xsv[i];
        while (m) {
            int i0 = (int)__builtin_ctzll(m);             m &= m - 1;
            bool h1 = m != 0;
            int i1 = m ? (int)__builtin_ctzll(m) : 0;     m &= m - 1;
            bool h2 = m != 0;
            int i2 = m ? (int)__builtin_ctzll(m) : 0;     m &= m - 1;
            bool h3 = m != 0;
            int i3 = m ? (int)__builtin_ctzll(m) : 0;     m &= m - 1;
            // 4 LDS W-row reads (stride-65 rows: 2-way alias = free)
            float W0 = Wl[(cb9 + i0) * WSTRIDE + lane];
            float W1 = Wl[(cb9 + i1) * WSTRIDE + lane];
            float W2 = Wl[(cb9 + i2) * WSTRIDE + lane];
            float W3 = Wl[(cb9 + i3) * WSTRIDE + lane];
            EKV_BODY(i0, W0, true)
            EKV_BODY(i1, W1, h1)
            EKV_BODY(i2, W2, h2)
            EKV_BODY(i3, W3, h3)
        }
    }
#undef EKV_BODY

    out[((n * NO + lane) * HH + ho) * WW + wo] = (accF - accR) * OS;
}

extern "C" void kernel_launch(void* const* d_in, const int* in_sizes, int n_in,
                              void* d_out, int out_size, void* d_ws, size_t ws_size,
                              hipStream_t stream) {
    const float* x     = (const float*)d_in[0];   // (4,64,32,32) fp32
    const float* theta = (const float*)d_in[1];   // (64,64,3,3) fp32
    float* out = (float*)d_out;                   // (4,64,32,32) fp32

    ekv_kernel<<<256, 1024, 0, stream>>>(x, theta, out);  // single dispatch
}